// Round 5
// baseline (115.121 us; speedup 1.0000x reference)
//
#include <hip/hip_runtime.h>

#define D 64
#define K 1024
#define NPTS 65536
#define OUT_ELEMS (NPTS * D)

typedef _Float16 f16x8 __attribute__((ext_vector_type(8)));
typedef float    f32x4 __attribute__((ext_vector_type(4)));

#define SCL  4096.0f            // 2^12
#define ISCL 0.000244140625f    // 2^-12

// d_ws layout (bytes): eT f32[K][64] @0 (262144) | enorm_half f32[K] @262144
// (4096) | ehf f16 frag-major @266240 (131072) | elf @397312 | end 528384.
//
// Fragment-major layout: for code k, dim d:
//   ct=k>>4, col=k&15, HH=d>>5, r=(d>>3)&3, j=d&7, lane=r*16+col
//   off = ((ct*2+HH)*64 + lane)*8 + j
// Main-loop lane (quad,m) reads its 16B f16x8 B-fragment for tile ct,
// K-half HH at ehf + (ct*2+HH)*512 + lane*8.

// Scaled f16 2-way split: v = h + ls*2^-12. h = RN16(v); ls = RN16((v-h)*2^12)
// is normal-range -> no subnormal-flush hazard; residual ~2^-24|v|.
static __device__ __forceinline__ void split16(float v, _Float16& h, _Float16& ls) {
    h = (_Float16)v;
    const float r = (v - (float)h) * SCL;   // exact scaling (pow2)
    ls = (_Float16)r;
}

// ---------------------------------------------------------------------------
// Prep: tiled transpose emb[D][K] -> eT[K][D] f32 (exact rows for the output
// gather) + fragment-major f16 h/ls arrays + enorm_half[k] = 0.5*||e_k||^2 in
// numpy axis-0 order; zero the loss slot.
// ---------------------------------------------------------------------------
__global__ __launch_bounds__(256) void vq_prep(const float* __restrict__ emb,
                                               float* __restrict__ eT,
                                               float* __restrict__ enorm_h,
                                               _Float16* __restrict__ ehf,
                                               _Float16* __restrict__ elf,
                                               float* __restrict__ loss_out) {
    __shared__ float tile[64][65];
    const int t    = threadIdx.x;
    const int lane = t & 63;
    const int quad = t >> 6;
    const int k0   = blockIdx.x * 64;

#pragma unroll
    for (int i = 0; i < 16; ++i) {
        const int d = i * 4 + quad;
        tile[d][lane] = emb[d * K + k0 + lane];
    }
    __syncthreads();

    const int kk = t >> 2, c = t & 3;
    const int krow = k0 + kk;
    const int ct   = krow >> 4, col = krow & 15;
#pragma unroll
    for (int j = 0; j < 16; ++j) {
        const int d = c * 16 + j;
        const float v = tile[d][kk];
        eT[krow * D + d] = v;
        _Float16 h, ls;
        split16(v, h, ls);
        const int off = ((ct * 2 + (d >> 5)) * 64 + ((d >> 3) & 3) * 16 + col) * 8
                        + (d & 7);
        ehf[off] = h; elf[off] = ls;
    }

    if (t < 64) {   // np add.reduce axis 0: sequential over d
        float s = __fmul_rn(tile[0][t], tile[0][t]);
        for (int dd = 1; dd < D; ++dd)
            s = __fadd_rn(s, __fmul_rn(tile[dd][t], tile[dd][t]));
        enorm_h[k0 + t] = 0.5f * s;
    }
    if (blockIdx.x == 0 && t == 0) *loss_out = 0.0f;
}

static __device__ __forceinline__ float sq8(float a, float b, float c, float d,
                                            float e, float f, float g, float h) {
    float r = __fmul_rn(a, a);
    r = __fadd_rn(r, __fmul_rn(b, b));
    r = __fadd_rn(r, __fmul_rn(c, c));
    r = __fadd_rn(r, __fmul_rn(d, d));
    r = __fadd_rn(r, __fmul_rn(e, e));
    r = __fadd_rn(r, __fmul_rn(f, f));
    r = __fadd_rn(r, __fmul_rn(g, g));
    r = __fadd_rn(r, __fmul_rn(h, h));
    return r;
}

#define PINF(v) asm volatile("" : "+v"(v))

#define MF(A, B, C) __builtin_amdgcn_mfma_f32_16x16x32_f16(A, B, C, 0, 0, 0)

#define MKFRAG16(FH, FS, U0, U1) {                        \
    _Float16 h_, s_;                                      \
    split16(U0.x, h_, s_); FH[0]=h_; FS[0]=s_;            \
    split16(U0.y, h_, s_); FH[1]=h_; FS[1]=s_;            \
    split16(U0.z, h_, s_); FH[2]=h_; FS[2]=s_;            \
    split16(U0.w, h_, s_); FH[3]=h_; FS[3]=s_;            \
    split16(U1.x, h_, s_); FH[4]=h_; FS[4]=s_;            \
    split16(U1.y, h_, s_); FH[5]=h_; FS[5]=s_;            \
    split16(U1.z, h_, s_); FH[6]=h_; FS[6]=s_;            \
    split16(U1.w, h_, s_); FH[7]=h_; FS[7]=s_; }

// ---------------------------------------------------------------------------
// Main (R16): double the per-wave M-tile (32 -> 64 points, 4 rowtiles).
// R13-R15 evidence: LDS-staged and global-load variants both stall at ~45us
// with MfmaUtil ~23% / VALUBusy ~29% -- the common wall is OPERAND DELIVERY
// bandwidth: 16 waves/CU x 4KB of B-fragments per 16-code tile = 64KB/CU/tile
// through L1 (~1000+ cyc) > MFMA pipe time (932 cyc). Fix: each wave now
// reuses its 4 B-fragment loads across 4 rowtiles (24 MFMA per 4KB instead
// of 12), and waves/CU halve (8) -> B-traffic 32KB/CU/tile, MFMA work/CU
// unchanged -> matrix pipe becomes the binding resource.
//   - block = 256 thr = 4 waves (2 point-groups x 2 code-halves), 128 pts.
//   - grid = 512 = 2 blocks/CU; launch_bounds(256,2) -> 256-reg budget
//     (everything in arch VGPRs, no AGPR-move traffic).
//   - argmin epilogue: 16-lane __shfl_xor lex-reduce in registers replaces
//     the 67KB skey/sct LDS arrays + 32-iter phase-C scan (LDS now 6.6KB).
// Numerics bit-identical to R15: same frag bits, same MFMA chains per
// (point,code), same combine, same global lex-(key,idx) winner, same
// 64-point-per-atomic loss grouping.
// ---------------------------------------------------------------------------
__global__ __launch_bounds__(256, 2) void vq_main(const float* __restrict__ x,
        const float* __restrict__ eT, const float* __restrict__ enorm_h,
        const _Float16* __restrict__ ehf, const _Float16* __restrict__ elf,
        float* __restrict__ out, float* __restrict__ loss_out) {
    // LDS: rpart 128x8 f32 @0 (4096) | swin 128 i32 @4096 (512) |
    //      sbk 2x128 f32 @4608 (1024) | sbi 2x128 i32 @5632 (1024) | end 6656.
    __shared__ __align__(16) char smem[6656];
    float* rpart = (float*)smem;
    int*   swin  = (int*)(smem + 4096);
    float* sbk   = (float*)(smem + 4608);
    int*   sbi   = (int*)(smem + 5632);

    const int t     = threadIdx.x;
    const int lane  = t & 63;
    const int w     = t >> 6;          // 0..3
    const int m     = lane & 15;
    const int quad  = lane >> 4;
    const int g     = w >> 1;          // point-group 0..1 (64 pts each)
    const int h     = w & 1;           // code-half 0..1
    const int pbase = blockIdx.x * 128 + g * 64;

    // ---- Phase A: x -> norm partials + 32 pinned A-frags (4 rowtiles) ----
    f16x8 Ah0_0, Ah0_1, As0_0, As0_1;
    f16x8 Ah1_0, Ah1_1, As1_0, As1_1;
    f16x8 Ah2_0, Ah2_1, As2_0, As2_1;
    f16x8 Ah3_0, Ah3_1, As3_0, As3_1;
#define LOADA(TT, HH, FH, FS) {                                            \
    const float* px = x + ((size_t)(pbase + TT * 16 + m)) * D + HH * 32 + quad * 8; \
    const float4 u0 = *(const float4*)px;                                  \
    const float4 u1 = *(const float4*)(px + 4);                            \
    if (h == 0)                                                            \
        rpart[(g * 64 + TT * 16 + m) * 8 + (HH * 4 + quad)] =              \
            sq8(u0.x, u0.y, u0.z, u0.w, u1.x, u1.y, u1.z, u1.w);           \
    MKFRAG16(FH, FS, u0, u1); }
    LOADA(0, 0, Ah0_0, As0_0)  LOADA(0, 1, Ah0_1, As0_1)
    LOADA(1, 0, Ah1_0, As1_0)  LOADA(1, 1, Ah1_1, As1_1)
    LOADA(2, 0, Ah2_0, As2_0)  LOADA(2, 1, Ah2_1, As2_1)
    LOADA(3, 0, Ah3_0, As3_0)  LOADA(3, 1, Ah3_1, As3_1)
#undef LOADA
    PINF(Ah0_0); PINF(Ah0_1); PINF(As0_0); PINF(As0_1);
    PINF(Ah1_0); PINF(Ah1_1); PINF(As1_0); PINF(As1_1);
    PINF(Ah2_0); PINF(Ah2_1); PINF(As2_0); PINF(As2_1);
    PINF(Ah3_0); PINF(Ah3_1); PINF(As3_0); PINF(As3_1);

    f32x4 ZERO = {0.f, 0.f, 0.f, 0.f};
    PINF(ZERO);

    // ---- Phase B: 32 tiles x 16 codes, reg-pipelined one tile ahead ----
    const float FINF = 3.402823466e38f;
    float bk0_0 = FINF, bk0_1 = FINF, bk0_2 = FINF, bk0_3 = FINF;
    float bk1_0 = FINF, bk1_1 = FINF, bk1_2 = FINF, bk1_3 = FINF;
    float bk2_0 = FINF, bk2_1 = FINF, bk2_2 = FINF, bk2_3 = FINF;
    float bk3_0 = FINF, bk3_1 = FINF, bk3_2 = FINF, bk3_3 = FINF;
    int   bc0_0 = 0, bc0_1 = 0, bc0_2 = 0, bc0_3 = 0;
    int   bc1_0 = 0, bc1_1 = 0, bc1_2 = 0, bc1_3 = 0;
    int   bc2_0 = 0, bc2_1 = 0, bc2_2 = 0, bc2_3 = 0;
    int   bc3_0 = 0, bc3_1 = 0, bc3_2 = 0, bc3_3 = 0;

    const char* bh = (const char*)ehf + (size_t)h * 65536 + (size_t)lane * 16;
    const char* bs = (const char*)elf + (size_t)h * 65536 + (size_t)lane * 16;
    const float* enp = enorm_h + h * 512 + m;

#define AC1(BK, BC, MV, CV, CT, ENH) {                                     \
    const float kv = __builtin_fmaf(-ISCL, CV, (ENH) - (MV));              \
    if (kv < BK) { BK = kv; BC = (CT); } }

#define COMPUTE(CT, BH0, BH1, BS0, BS1, ENH) {                             \
    f32x4 m0 = MF(Ah0_0, BH0, ZERO);  f32x4 m1 = MF(Ah1_0, BH0, ZERO);     \
    f32x4 m2 = MF(Ah2_0, BH0, ZERO);  f32x4 m3 = MF(Ah3_0, BH0, ZERO);     \
    f32x4 c0 = MF(As0_0, BH0, ZERO);  f32x4 c1 = MF(As1_0, BH0, ZERO);     \
    f32x4 c2 = MF(As2_0, BH0, ZERO);  f32x4 c3 = MF(As3_0, BH0, ZERO);     \
    m0 = MF(Ah0_1, BH1, m0);  m1 = MF(Ah1_1, BH1, m1);                     \
    m2 = MF(Ah2_1, BH1, m2);  m3 = MF(Ah3_1, BH1, m3);                     \
    c0 = MF(As0_1, BH1, c0);  c1 = MF(As1_1, BH1, c1);                     \
    c2 = MF(As2_1, BH1, c2);  c3 = MF(As3_1, BH1, c3);                     \
    c0 = MF(Ah0_0, BS0, c0);  c1 = MF(Ah1_0, BS0, c1);                     \
    c2 = MF(Ah2_0, BS0, c2);  c3 = MF(Ah3_0, BS0, c3);                     \
    c0 = MF(Ah0_1, BS1, c0);  c1 = MF(Ah1_1, BS1, c1);                     \
    c2 = MF(Ah2_1, BS1, c2);  c3 = MF(Ah3_1, BS1, c3);                     \
    AC1(bk0_0, bc0_0, m0[0], c0[0], CT, ENH)                               \
    AC1(bk0_1, bc0_1, m0[1], c0[1], CT, ENH)                               \
    AC1(bk0_2, bc0_2, m0[2], c0[2], CT, ENH)                               \
    AC1(bk0_3, bc0_3, m0[3], c0[3], CT, ENH)                               \
    AC1(bk1_0, bc1_0, m1[0], c1[0], CT, ENH)                               \
    AC1(bk1_1, bc1_1, m1[1], c1[1], CT, ENH)                               \
    AC1(bk1_2, bc1_2, m1[2], c1[2], CT, ENH)                               \
    AC1(bk1_3, bc1_3, m1[3], c1[3], CT, ENH)                               \
    AC1(bk2_0, bc2_0, m2[0], c2[0], CT, ENH)                               \
    AC1(bk2_1, bc2_1, m2[1], c2[1], CT, ENH)                               \
    AC1(bk2_2, bc2_2, m2[2], c2[2], CT, ENH)                               \
    AC1(bk2_3, bc2_3, m2[3], c2[3], CT, ENH)                               \
    AC1(bk3_0, bc3_0, m3[0], c3[0], CT, ENH)                               \
    AC1(bk3_1, bc3_1, m3[1], c3[1], CT, ENH)                               \
    AC1(bk3_2, bc3_2, m3[2], c3[2], CT, ENH)                               \
    AC1(bk3_3, bc3_3, m3[3], c3[3], CT, ENH) }

#define LOADB(TT, BH0, BH1, BS0, BS1, ENH) {                               \
    const int ob_ = (TT) * 2048;                                           \
    BH0 = *(const f16x8*)(bh + ob_);        BH1 = *(const f16x8*)(bh + ob_ + 1024); \
    BS0 = *(const f16x8*)(bs + ob_);        BS1 = *(const f16x8*)(bs + ob_ + 1024); \
    ENH = enp[(TT) * 16]; }

    f16x8 aBh0, aBh1, aBs0, aBs1;  float aEn;   // buffer A
    f16x8 pBh0, pBh1, pBs0, pBs1;  float pEn;   // buffer B

    LOADB(0, aBh0, aBh1, aBs0, aBs1, aEn)       // prologue: tile 0 -> A
    for (int j = 0; j < 16; ++j) {
        const int t1 = 2 * j + 1;
        const int t2 = (2 * j + 2) & 31;        // wrap: harmless re-read
        LOADB(t1, pBh0, pBh1, pBs0, pBs1, pEn)  // prefetch odd tile -> B
        COMPUTE(2 * j, aBh0, aBh1, aBs0, aBs1, aEn)
        LOADB(t2, aBh0, aBh1, aBs0, aBs1, aEn)  // prefetch even tile -> A
        COMPUTE(t1, pBh0, pBh1, pBs0, pBs1, pEn)
    }
#undef LOADB
#undef COMPUTE
#undef AC1

    // ---- Argmin epilogue: 16-lane lex (key, idx) reduce in registers.
    // Per point p the 16 candidate classes (columns m) live across the 16
    // lanes of its quad-group; xor-shuffle tree yields the same global
    // lex-min as the old skey/sct scan. idx = h*512 + bc*16 + m.
#define LEXSTEP(KV, IV, MSK) {                                             \
    const float ok_ = __shfl_xor(KV, MSK, 64);                             \
    const int   oi_ = __shfl_xor(IV, MSK, 64);                             \
    if (ok_ < KV || (ok_ == KV && oi_ < IV)) { KV = ok_; IV = oi_; } }
#define REDUCE1(BK, BC, TT, EE) {                                          \
    float kv = BK; int iv = h * 512 + BC * 16 + m;                         \
    LEXSTEP(kv, iv, 1) LEXSTEP(kv, iv, 2)                                  \
    LEXSTEP(kv, iv, 4) LEXSTEP(kv, iv, 8)                                  \
    if (m == 0) {                                                          \
        const int p = g * 64 + (TT) * 16 + quad * 4 + (EE);                \
        sbk[h * 128 + p] = kv; sbi[h * 128 + p] = iv; } }
    REDUCE1(bk0_0, bc0_0, 0, 0) REDUCE1(bk0_1, bc0_1, 0, 1)
    REDUCE1(bk0_2, bc0_2, 0, 2) REDUCE1(bk0_3, bc0_3, 0, 3)
    REDUCE1(bk1_0, bc1_0, 1, 0) REDUCE1(bk1_1, bc1_1, 1, 1)
    REDUCE1(bk1_2, bc1_2, 1, 2) REDUCE1(bk1_3, bc1_3, 1, 3)
    REDUCE1(bk2_0, bc2_0, 2, 0) REDUCE1(bk2_1, bc2_1, 2, 1)
    REDUCE1(bk2_2, bc2_2, 2, 2) REDUCE1(bk2_3, bc2_3, 2, 3)
    REDUCE1(bk3_0, bc3_0, 3, 0) REDUCE1(bk3_1, bc3_1, 3, 1)
    REDUCE1(bk3_2, bc3_2, 3, 2) REDUCE1(bk3_3, bc3_3, 3, 3)
#undef REDUCE1
#undef LEXSTEP
    __syncthreads();

    // ---- Phase C (t<128): combine the two code-halves, loss partial ----
    if (t < 128) {
        const int p = t;
        const float* rp = rpart + p * 8;
        const float A = ((rp[0] + rp[1]) + (rp[2] + rp[3])) +
                        ((rp[4] + rp[5]) + (rp[6] + rp[7]));
        float fb = sbk[p];        int fi = sbi[p];          // h = 0
        const float k1 = sbk[128 + p]; const int i1 = sbi[128 + p];
        if (k1 < fb || (k1 == fb && i1 < fi)) { fb = k1; fi = i1; }
        swin[p] = fi;
        float lp = fmaf(2.0f, fb, A);   // ||x-q||^2 = A + 2*key
#pragma unroll
        for (int off = 32; off > 0; off >>= 1) lp += __shfl_down(lp, off, 64);
        if (lane == 0) atomicAdd(loss_out, lp * (1.25f / (float)OUT_ELEMS));
    }
    __syncthreads();

    // ---- Phase D: direct coalesced gather-write. 16 consecutive lanes
    // write the 16 float4 chunks of one point; eT row is 256B contiguous
    // from L2-resident eT. Bit-exact row copy. ----
    {
        const float4* eT4 = (const float4*)eT;
        float4* og = (float4*)out + (size_t)blockIdx.x * 2048;
#pragma unroll
        for (int s = 0; s < 8; ++s) {
            const int f  = s * 256 + t;          // 0..2047 float4s
            const int fi = swin[f >> 4];
            og[f] = eT4[(size_t)fi * 16 + (f & 15)];
        }
    }
}

extern "C" void kernel_launch(void* const* d_in, const int* in_sizes, int n_in,
                              void* d_out, int out_size, void* d_ws, size_t ws_size,
                              hipStream_t stream) {
    const float* x   = (const float*)d_in[0];   // [64,32,32,64] fp32
    const float* emb = (const float*)d_in[1];   // [64,1024] fp32
    float* out       = (float*)d_out;           // [quantized | loss]
    char*  ws        = (char*)d_ws;             // needs 528384 B
    float*    eT      = (float*)ws;
    float*    enorm_h = (float*)(ws + 262144);
    _Float16* ehf     = (_Float16*)(ws + 266240);
    _Float16* elf     = (_Float16*)(ws + 397312);
    float* loss_out   = out + OUT_ELEMS;

    vq_prep<<<dim3(K / 64), dim3(256), 0, stream>>>(emb, eT, enorm_h, ehf, elf,
                                                    loss_out);
    vq_main<<<dim3(NPTS / 128), dim3(256), 0, stream>>>(x, eT, enorm_h, ehf,
                                                        elf, out, loss_out);
}